// Round 1
// baseline (154.810 us; speedup 1.0000x reference)
//
#include <hip/hip_runtime.h>
#include <hip/hip_bf16.h>

#define BATCH 16384
#define FIN   768
#define FOUT  512

#define BK 32
#define NT (FIN / BK)   // 24 K-iterations

typedef __attribute__((ext_vector_type(8))) short short8;
typedef __attribute__((ext_vector_type(4))) float floatx4;

// packed fp32x2 -> bf16x2, round-to-nearest-even (gfx940+ VOP3)
__device__ __forceinline__ unsigned int cvt_pk_bf16(float a, float b) {
    unsigned int r;
    asm("v_cvt_pk_bf16_f32 %0, %1, %2" : "=v"(r) : "v"(a), "v"(b));
    return r;
}

// async 16B global -> LDS DMA; HW scatters lane i to ldsbase + i*16
__device__ __forceinline__ void load_lds_16(const void* g, void* l) {
    __builtin_amdgcn_global_load_lds(
        (const __attribute__((address_space(1))) unsigned int*)g,
        (__attribute__((address_space(3))) unsigned int*)l,
        16, 0, 0);
}

// one-shot W1 fp32 -> bf16 (393216 elems, 8 per thread, 192 blocks)
__global__ __launch_bounds__(256) void cvt_w1(
    const float* __restrict__ W1, unsigned short* __restrict__ W1b)
{
    int base = (blockIdx.x * 256 + threadIdx.x) * 8;
    float4 a = *(const float4*)(W1 + base);
    float4 b = *(const float4*)(W1 + base + 4);
    uint4 o;
    o.x = cvt_pk_bf16(a.x, a.y); o.y = cvt_pk_bf16(a.z, a.w);
    o.z = cvt_pk_bf16(b.x, b.y); o.w = cvt_pk_bf16(b.z, b.w);
    *(uint4*)(W1b + base) = o;
}

// 512 blocks x 512 threads: 2 co-resident blocks per CU (72 KB LDS each,
// ~124 combined VGPR+AGPR -> 4 waves/SIMD). Each block: 32 batch rows x both
// perspectives (64 GEMM rows: 0-31 = stm, 32-63 = nstm) x all 512 features.
// 8 waves, each owning a 64x64 output tile (4x4 frags of 16x16x32 bf16 MFMA).
// Same verified single-barrier double-buffered K-loop as the 148 us kernel:
//   [publish A(t)] barrier [issue B-DMA(t+1) + A-load(t+1)] [MFMA tile t]
// The second resident block's compute overlaps this block's barrier drain /
// HBM latency, which the 1-block/CU version could not hide.
// LDS XOR-swizzle (slot = chunk ^ (row&3)) identical on store & read sides.
__global__ __launch_bounds__(512, 4) void pn_gemm(
    const float* __restrict__ stm, const float* __restrict__ nstm,
    const unsigned short* __restrict__ W1b, const float* __restrict__ b1,
    const float* __restrict__ W2, const float* __restrict__ b2,
    float* __restrict__ out)
{
    __shared__ __align__(16) unsigned short As[2][64 * 32];   // 2 x 4 KB
    __shared__ __align__(16) unsigned short Bs[2][512 * 32];  // 2 x 32 KB

    const int tid  = threadIdx.x;
    const int lane = tid & 63;
    const int wave = tid >> 6;    // 0..7 — col tile: cols wave*64 .. +63
    const int quad = lane >> 4;
    const int l16  = lane & 15;
    const int l3   = l16 & 3;

    const int b0 = blockIdx.x * 32;   // batch rows owned by this block

    // ---- A staging (waves 0-3 only): thread covers row arow, chunk ach
    const int arow = tid >> 2;        // 0..63 (valid for tid < 256)
    const int ach  = tid & 3;         // 8-elem chunk within the 32-k tile
    const float* aSrc = nullptr;
    if (tid < 256)
        aSrc = ((arow < 32) ? stm  + (size_t)(b0 + arow) * FIN
                            : nstm + (size_t)(b0 + arow - 32) * FIN) + ach * 8;
    const int aOff = arow * 32 + (ach ^ (arow & 3)) * 8;   // swizzled dest

    // ---- B staging: 4 DMA instrs/wave, J = wave*4+i covers rows J*16..+15
    const int brow = lane >> 2;                 // row within 16-group
    const int bch  = (lane & 3) ^ (brow & 3);   // swizzled SOURCE chunk

    floatx4 acc[4][4];
    #pragma unroll
    for (int i = 0; i < 4; ++i)
        #pragma unroll
        for (int j = 0; j < 4; ++j)
            acc[i][j] = (floatx4)0.0f;

    // ---- prologue: stage tile 0
    float4 ap0, ap1;
    if (tid < 256) {
        ap0 = *(const float4*)(aSrc);
        ap1 = *(const float4*)(aSrc + 4);
    }
    #pragma unroll
    for (int i = 0; i < 4; ++i) {
        const int J = wave * 4 + i;
        load_lds_16(W1b + (size_t)(J * 16 + brow) * FIN + bch * 8,
                    &Bs[0][J * 16 * 32]);
    }

    for (int t = 0; t < NT; ++t) {
        const int cur = t & 1;
        const int nxt = cur ^ 1;

        // publish A(t) (regs loaded last iter; As[cur] reads drained at barrier t-1)
        if (tid < 256) {
            uint4 o;
            o.x = cvt_pk_bf16(ap0.x, ap0.y); o.y = cvt_pk_bf16(ap0.z, ap0.w);
            o.z = cvt_pk_bf16(ap1.x, ap1.y); o.w = cvt_pk_bf16(ap1.z, ap1.w);
            *(uint4*)(&As[cur][aOff]) = o;
        }
        __syncthreads();   // drains B-DMA(t) + A-store(t); protects tile t-1 buffers

        // issue staging for t+1 — lands during tile t's compute
        if (t + 1 < NT) {
            const int kn = (t + 1) * BK;
            #pragma unroll
            for (int i = 0; i < 4; ++i) {
                const int J = wave * 4 + i;
                load_lds_16(W1b + (size_t)(J * 16 + brow) * FIN + kn + bch * 8,
                            &Bs[nxt][J * 16 * 32]);
            }
            if (tid < 256) {
                ap0 = *(const float4*)(aSrc + kn);
                ap1 = *(const float4*)(aSrc + kn + 4);
            }
        }

        // compute tile t
        short8 af[4], bfr[4];
        #pragma unroll
        for (int mi = 0; mi < 4; ++mi) {
            const int m = mi * 16 + l16;
            af[mi] = *(const short8*)(&As[cur][m * 32 + ((quad ^ l3) * 8)]);
        }
        #pragma unroll
        for (int ni = 0; ni < 4; ++ni) {
            const int n = wave * 64 + ni * 16 + l16;
            bfr[ni] = *(const short8*)(&Bs[cur][n * 32 + ((quad ^ l3) * 8)]);
        }
        #pragma unroll
        for (int mi = 0; mi < 4; ++mi)
            #pragma unroll
            for (int ni = 0; ni < 4; ++ni)
                acc[mi][ni] = __builtin_amdgcn_mfma_f32_16x16x32_bf16(
                    af[mi], bfr[ni], acc[mi][ni], 0, 0, 0);
    }

    // ---- fused epilogue. C/D layout: col = lane&15, row = quad*4 + reg.
    // Rows 0-31 (mi 0,1) = stm perspective -> W2[0..511];
    // rows 32-63 (mi 2,3) = nstm perspective -> W2[512..1023].
    float b1v[4], w2s[4], w2n[4];
    #pragma unroll
    for (int ni = 0; ni < 4; ++ni) {
        int col = wave * 64 + ni * 16 + l16;
        b1v[ni] = b1[col];
        w2s[ni] = W2[col];
        w2n[ni] = W2[FOUT + col];
    }

    __syncthreads();                 // all MFMA LDS reads done; reuse As
    float* Epi = (float*)As;         // [64 rows][8 wave-cols] partials (2 KB)

    #pragma unroll
    for (int mi = 0; mi < 4; ++mi) {
        #pragma unroll
        for (int r = 0; r < 4; ++r) {
            float s = 0.0f;
            #pragma unroll
            for (int ni = 0; ni < 4; ++ni) {
                float h = acc[mi][ni][r] + b1v[ni];
                h = fminf(fmaxf(h, 0.0f), 1.0f);
                s += h * ((mi < 2) ? w2s[ni] : w2n[ni]);
            }
            s += __shfl_xor(s, 1);
            s += __shfl_xor(s, 2);
            s += __shfl_xor(s, 4);
            s += __shfl_xor(s, 8);
            if (l16 == 0) {
                Epi[(mi * 16 + quad * 4 + r) * 8 + wave] = s;
            }
        }
    }
    __syncthreads();

    if (tid < 32) {
        float x = b2[0];
        #pragma unroll
        for (int j = 0; j < 8; ++j)
            x += Epi[tid * 8 + j] + Epi[(tid + 32) * 8 + j];
        out[b0 + tid] = 1.0f / (1.0f + expf(-x));
    }
}

extern "C" void kernel_launch(void* const* d_in, const int* in_sizes, int n_in,
                              void* d_out, int out_size, void* d_ws, size_t ws_size,
                              hipStream_t stream)
{
    (void)in_sizes; (void)n_in; (void)out_size; (void)ws_size;
    const float* stm  = (const float*)d_in[0];
    const float* nstm = (const float*)d_in[1];
    const float* W1   = (const float*)d_in[2];
    const float* b1   = (const float*)d_in[3];
    const float* W2   = (const float*)d_in[4];
    const float* b2   = (const float*)d_in[5];
    float* out = (float*)d_out;
    unsigned short* W1b = (unsigned short*)d_ws;   // bf16 W1 copy (768 KB)

    cvt_w1<<<dim3((FOUT * FIN) / (256 * 8)), dim3(256), 0, stream>>>(W1, W1b);
    pn_gemm<<<dim3(BATCH / 32), dim3(512), 0, stream>>>(
        stm, nstm, W1b, b1, W2, b2, out);
}

// Round 2
// 154.348 us; speedup vs baseline: 1.0030x; 1.0030x over previous
//
#include <hip/hip_runtime.h>
#include <hip/hip_bf16.h>

#define BATCH 16384
#define FIN   768
#define FOUT  512

#define BK 32
#define NT (FIN / BK)   // 24 K-iterations
#define BM 128          // batch rows per block -> 256 GEMM rows (stm+nstm)
#define BN 256          // feature cols per block (N-split x2)

typedef __attribute__((ext_vector_type(8))) short short8;
typedef __attribute__((ext_vector_type(4))) float floatx4;

// packed fp32x2 -> bf16x2, round-to-nearest-even (gfx940+ VOP3)
__device__ __forceinline__ unsigned int cvt_pk_bf16(float a, float b) {
    unsigned int r;
    asm("v_cvt_pk_bf16_f32 %0, %1, %2" : "=v"(r) : "v"(a), "v"(b));
    return r;
}

// async 16B global -> LDS DMA; HW scatters lane i to ldsbase + i*16
__device__ __forceinline__ void load_lds_16(const void* g, void* l) {
    __builtin_amdgcn_global_load_lds(
        (const __attribute__((address_space(1))) unsigned int*)g,
        (__attribute__((address_space(3))) unsigned int*)l,
        16, 0, 0);
}

// one-shot W1 fp32 -> bf16 (393216 elems, 8 per thread, 192 blocks)
__global__ __launch_bounds__(256) void cvt_w1(
    const float* __restrict__ W1, unsigned short* __restrict__ W1b)
{
    int base = (blockIdx.x * 256 + threadIdx.x) * 8;
    float4 a = *(const float4*)(W1 + base);
    float4 b = *(const float4*)(W1 + base + 4);
    uint4 o;
    o.x = cvt_pk_bf16(a.x, a.y); o.y = cvt_pk_bf16(a.z, a.w);
    o.z = cvt_pk_bf16(b.x, b.y); o.w = cvt_pk_bf16(b.z, b.w);
    *(uint4*)(W1b + base) = o;
}

// 256 blocks x 1024 threads, 1 block/CU. Tile rebalanced vs the 148us kernel:
// BM=128 batch rows (256 GEMM rows: 0-127 stm, 128-255 nstm) x BN=256
// features, N-split x2 across blocks. Halves per-iter B staging (32->16 KB
// from L2 + LDS-write), halves aggregate W1 L2 traffic (201->98 MB); A-tile
// grows to 16 KB/iter (L3-resident, cheap) staged by ALL 16 waves.
// Schedule, swizzles, wave tile (64x64, 4x4 frags of 16x16x32 bf16 MFMA)
// carried over verbatim from the verified kernel:
//   [publish A(t)] barrier [issue B-DMA(t+1) + A-load(t+1)] [MFMA tile t]
// Epilogue writes pre-sigmoid partials over this block's 256 features to
// workspace; tiny finish kernel sums the two N-halves + sigmoid.
__global__ __launch_bounds__(1024, 4) void pn_gemm(
    const float* __restrict__ stm, const float* __restrict__ nstm,
    const unsigned short* __restrict__ W1b, const float* __restrict__ b1,
    const float* __restrict__ W2, float* __restrict__ P)
{
    __shared__ __align__(16) unsigned short As[2][256 * 32];  // 2 x 16 KB
    __shared__ __align__(16) unsigned short Bs[2][256 * 32];  // 2 x 16 KB

    const int tid  = threadIdx.x;
    const int lane = tid & 63;
    const int wave = tid >> 6;    // 0..15
    const int wr   = wave >> 2;   // row tile: GEMM rows wr*64 .. +63
    const int wc   = wave & 3;    // col tile: cols wc*64 .. +63 (within BN)
    const int quad = lane >> 4;
    const int l16  = lane & 15;
    const int l3   = l16 & 3;

    const int bm    = blockIdx.x >> 1;
    const int n_idx = blockIdx.x & 1;
    const int b0    = bm * BM;        // batch rows owned by this block
    const int n0    = n_idx * BN;     // feature cols owned by this block

    // ---- A staging: all 1024 threads, one row-chunk each
    const int arow = tid >> 2;        // 0..255
    const int ach  = tid & 3;         // 8-elem chunk within the 32-k tile
    const float* aSrc =
        ((arow < BM) ? stm  + (size_t)(b0 + arow) * FIN
                     : nstm + (size_t)(b0 + arow - BM) * FIN) + ach * 8;
    const int aOff = arow * 32 + (ach ^ (arow & 3)) * 8;   // swizzled dest

    // ---- B staging: 1 DMA instr/wave, wave covers rows wave*16..+15
    const int brow = lane >> 2;                 // row within 16-group
    const int bch  = (lane & 3) ^ (brow & 3);   // swizzled SOURCE chunk
    const unsigned short* bSrc =
        W1b + (size_t)(n0 + wave * 16 + brow) * FIN + bch * 8;

    floatx4 acc[4][4];
    #pragma unroll
    for (int i = 0; i < 4; ++i)
        #pragma unroll
        for (int j = 0; j < 4; ++j)
            acc[i][j] = (floatx4)0.0f;

    // ---- prologue: stage tile 0
    float4 ap0 = *(const float4*)(aSrc);
    float4 ap1 = *(const float4*)(aSrc + 4);
    load_lds_16(bSrc, &Bs[0][wave * 512]);

    for (int t = 0; t < NT; ++t) {
        const int cur = t & 1;
        const int nxt = cur ^ 1;

        // publish A(t) (regs loaded last iter; As[cur] reads drained at barrier t-1)
        {
            uint4 o;
            o.x = cvt_pk_bf16(ap0.x, ap0.y); o.y = cvt_pk_bf16(ap0.z, ap0.w);
            o.z = cvt_pk_bf16(ap1.x, ap1.y); o.w = cvt_pk_bf16(ap1.z, ap1.w);
            *(uint4*)(&As[cur][aOff]) = o;
        }
        __syncthreads();   // drains B-DMA(t) + A-store(t); protects tile t-1 buffers

        // issue staging for t+1 — lands during tile t's compute
        if (t + 1 < NT) {
            const int kn = (t + 1) * BK;
            load_lds_16(bSrc + kn, &Bs[nxt][wave * 512]);
            ap0 = *(const float4*)(aSrc + kn);
            ap1 = *(const float4*)(aSrc + kn + 4);
        }

        // compute tile t
        short8 af[4], bfr[4];
        #pragma unroll
        for (int mi = 0; mi < 4; ++mi) {
            const int m = wr * 64 + mi * 16 + l16;
            af[mi] = *(const short8*)(&As[cur][m * 32 + ((quad ^ l3) * 8)]);
        }
        #pragma unroll
        for (int ni = 0; ni < 4; ++ni) {
            const int n = wc * 64 + ni * 16 + l16;
            bfr[ni] = *(const short8*)(&Bs[cur][n * 32 + ((quad ^ l3) * 8)]);
        }
        #pragma unroll
        for (int mi = 0; mi < 4; ++mi)
            #pragma unroll
            for (int ni = 0; ni < 4; ++ni)
                acc[mi][ni] = __builtin_amdgcn_mfma_f32_16x16x32_bf16(
                    af[mi], bfr[ni], acc[mi][ni], 0, 0, 0);
    }

    // ---- fused epilogue. C/D layout: col = lane&15, row = quad*4 + reg.
    // GEMM rows 0-127 (wr 0,1) = stm -> W2[0..511];
    // rows 128-255 (wr 2,3) = nstm -> W2[512..1023]. wr is wave-uniform.
    float b1v[4], w2v[4];
    const float* w2base = (wr < 2) ? W2 : W2 + FOUT;
    #pragma unroll
    for (int ni = 0; ni < 4; ++ni) {
        int col = n0 + wc * 64 + ni * 16 + l16;
        b1v[ni] = b1[col];
        w2v[ni] = w2base[col];
    }

    __syncthreads();                 // all MFMA LDS reads done; reuse As
    float* Epi = (float*)As;         // [256 rows][4 wave-cols] partials (4 KB)

    #pragma unroll
    for (int mi = 0; mi < 4; ++mi) {
        #pragma unroll
        for (int r = 0; r < 4; ++r) {
            float s = 0.0f;
            #pragma unroll
            for (int ni = 0; ni < 4; ++ni) {
                float h = acc[mi][ni][r] + b1v[ni];
                h = fminf(fmaxf(h, 0.0f), 1.0f);
                s += h * w2v[ni];
            }
            s += __shfl_xor(s, 1);
            s += __shfl_xor(s, 2);
            s += __shfl_xor(s, 4);
            s += __shfl_xor(s, 8);
            if (l16 == 0) {
                Epi[(wr * 64 + mi * 16 + quad * 4 + r) * 4 + wc] = s;
            }
        }
    }
    __syncthreads();

    // batch row i partial over this block's 256 features =
    // sum of stm-row i partials (rows 0-127) + nstm-row i partials (128-255)
    if (tid < BM) {
        float x = 0.0f;
        #pragma unroll
        for (int j = 0; j < 4; ++j)
            x += Epi[tid * 4 + j] + Epi[(tid + BM) * 4 + j];
        P[n_idx * BATCH + b0 + tid] = x;
    }
}

// sum the two N-half partials + bias, sigmoid
__global__ __launch_bounds__(256) void finish(
    const float* __restrict__ P, const float* __restrict__ b2,
    float* __restrict__ out)
{
    int i = blockIdx.x * 256 + threadIdx.x;
    float x = b2[0] + P[i] + P[BATCH + i];
    out[i] = 1.0f / (1.0f + expf(-x));
}

extern "C" void kernel_launch(void* const* d_in, const int* in_sizes, int n_in,
                              void* d_out, int out_size, void* d_ws, size_t ws_size,
                              hipStream_t stream)
{
    (void)in_sizes; (void)n_in; (void)out_size; (void)ws_size;
    const float* stm  = (const float*)d_in[0];
    const float* nstm = (const float*)d_in[1];
    const float* W1   = (const float*)d_in[2];
    const float* b1   = (const float*)d_in[3];
    const float* W2   = (const float*)d_in[4];
    const float* b2   = (const float*)d_in[5];
    float* out = (float*)d_out;
    unsigned short* W1b = (unsigned short*)d_ws;           // bf16 W1 (768 KB)
    float* P = (float*)((char*)d_ws + FOUT * FIN * 2);     // partials (128 KB)

    cvt_w1<<<dim3((FOUT * FIN) / (256 * 8)), dim3(256), 0, stream>>>(W1, W1b);
    pn_gemm<<<dim3((BATCH / BM) * 2), dim3(1024), 0, stream>>>(
        stm, nstm, W1b, b1, W2, P);
    finish<<<dim3(BATCH / 256), dim3(256), 0, stream>>>(P, b2, out);
}

// Round 3
// 146.170 us; speedup vs baseline: 1.0591x; 1.0560x over previous
//
#include <hip/hip_runtime.h>
#include <hip/hip_bf16.h>

#define BATCH 16384
#define FIN   768
#define FOUT  512

#define BK 64
#define NT (FIN / BK)   // 12 K-iterations
#define BM 128          // batch rows per block -> 256 GEMM rows (stm+nstm)
#define BN 256          // feature cols per block (N-split x2)

typedef __attribute__((ext_vector_type(8))) short short8;
typedef __attribute__((ext_vector_type(4))) float floatx4;

// packed fp32x2 -> bf16x2, round-to-nearest-even (gfx940+ VOP3)
__device__ __forceinline__ unsigned int cvt_pk_bf16(float a, float b) {
    unsigned int r;
    asm("v_cvt_pk_bf16_f32 %0, %1, %2" : "=v"(r) : "v"(a), "v"(b));
    return r;
}

// async 16B global -> LDS DMA; HW scatters lane i to ldsbase + i*16
__device__ __forceinline__ void load_lds_16(const void* g, void* l) {
    __builtin_amdgcn_global_load_lds(
        (const __attribute__((address_space(1))) unsigned int*)g,
        (__attribute__((address_space(3))) unsigned int*)l,
        16, 0, 0);
}

// one-shot W1 fp32 -> bf16 (393216 elems, 8 per thread, 192 blocks)
__global__ __launch_bounds__(256) void cvt_w1(
    const float* __restrict__ W1, unsigned short* __restrict__ W1b)
{
    int base = (blockIdx.x * 256 + threadIdx.x) * 8;
    float4 a = *(const float4*)(W1 + base);
    float4 b = *(const float4*)(W1 + base + 4);
    uint4 o;
    o.x = cvt_pk_bf16(a.x, a.y); o.y = cvt_pk_bf16(a.z, a.w);
    o.z = cvt_pk_bf16(b.x, b.y); o.w = cvt_pk_bf16(b.z, b.w);
    *(uint4*)(W1b + base) = o;
}

// 256 blocks x 1024 threads, 1 block/CU. Geometry as round-2 (BM=128 batch
// rows -> 256 GEMM rows: 0-127 stm, 128-255 nstm; BN=256 feature cols,
// N-split x2), but BK widened 32 -> 64 (NT 24 -> 12): measured per-iteration
// cost is ~2.2us FIXED (volume-insensitive across rounds 0-2), so halving
// the iteration count amortizes the structural barrier-drain overhead.
// LDS 128 KB (2x32 KB A + 2x32 KB B). K-tile = 8 chunks of 8 elems;
// XOR-swizzle slot = chunk ^ (row&7), same family as the verified kernel,
// applied on store/DMA-source and read sides identically.
// Schedule unchanged:
//   [publish A(t)] barrier [issue B-DMA(t+1) + A-load(t+1)] [MFMA tile t]
__global__ __launch_bounds__(1024, 4) void pn_gemm(
    const float* __restrict__ stm, const float* __restrict__ nstm,
    const unsigned short* __restrict__ W1b, const float* __restrict__ b1,
    const float* __restrict__ W2, float* __restrict__ P)
{
    __shared__ __align__(16) unsigned short As[2][256 * 64];  // 2 x 32 KB
    __shared__ __align__(16) unsigned short Bs[2][256 * 64];  // 2 x 32 KB

    const int tid  = threadIdx.x;
    const int lane = tid & 63;
    const int wave = tid >> 6;    // 0..15
    const int wr   = wave >> 2;   // row tile: GEMM rows wr*64 .. +63
    const int wc   = wave & 3;    // col tile: cols wc*64 .. +63 (within BN)
    const int quad = lane >> 4;
    const int l16  = lane & 15;

    const int bm    = blockIdx.x >> 1;
    const int n_idx = blockIdx.x & 1;
    const int b0    = bm * BM;        // batch rows owned by this block
    const int n0    = n_idx * BN;     // feature cols owned by this block

    // ---- A staging: thread covers row arow, chunks ac and ac+4 (16 fp32)
    const int arow = tid >> 2;        // 0..255
    const int ac   = tid & 3;         // low chunk; high chunk = ac+4
    const float* aSrc =
        ((arow < BM) ? stm  + (size_t)(b0 + arow) * FIN
                     : nstm + (size_t)(b0 + arow - BM) * FIN);
    const int aOffLo = arow * 64 + ((ac       ^ (arow & 7)) * 8);  // swizzled
    const int aOffHi = arow * 64 + (((ac + 4) ^ (arow & 7)) * 8);

    // ---- B staging: 2 DMA instrs/wave, J = wave*2+i covers rows J*8..+7.
    // DMA writes lane l -> base + l*16 (row l>>3, slot l&7); source chunk is
    // pre-swizzled so LDS holds slot = chunk ^ (row&7).
    const int brow = lane >> 3;                 // row within 8-group
    const int bch  = (lane & 7) ^ brow;         // swizzled SOURCE chunk
    const unsigned short* bSrc =
        W1b + (size_t)(n0 + brow) * FIN + bch * 8;

    floatx4 acc[4][4];
    #pragma unroll
    for (int i = 0; i < 4; ++i)
        #pragma unroll
        for (int j = 0; j < 4; ++j)
            acc[i][j] = (floatx4)0.0f;

    // ---- prologue: stage tile 0
    float4 ap0 = *(const float4*)(aSrc + ac * 8);
    float4 ap1 = *(const float4*)(aSrc + ac * 8 + 4);
    float4 ap2 = *(const float4*)(aSrc + (ac + 4) * 8);
    float4 ap3 = *(const float4*)(aSrc + (ac + 4) * 8 + 4);
    #pragma unroll
    for (int i = 0; i < 2; ++i) {
        const int J = wave * 2 + i;
        load_lds_16(bSrc + (size_t)(J * 8) * FIN, &Bs[0][J * 512]);
    }

    for (int t = 0; t < NT; ++t) {
        const int cur = t & 1;
        const int nxt = cur ^ 1;

        // publish A(t) (regs loaded last iter; As[cur] reads drained at barrier t-1)
        {
            uint4 o1, o2;
            o1.x = cvt_pk_bf16(ap0.x, ap0.y); o1.y = cvt_pk_bf16(ap0.z, ap0.w);
            o1.z = cvt_pk_bf16(ap1.x, ap1.y); o1.w = cvt_pk_bf16(ap1.z, ap1.w);
            o2.x = cvt_pk_bf16(ap2.x, ap2.y); o2.y = cvt_pk_bf16(ap2.z, ap2.w);
            o2.z = cvt_pk_bf16(ap3.x, ap3.y); o2.w = cvt_pk_bf16(ap3.z, ap3.w);
            *(uint4*)(&As[cur][aOffLo]) = o1;
            *(uint4*)(&As[cur][aOffHi]) = o2;
        }
        __syncthreads();   // drains B-DMA(t) + A-store(t); protects tile t-1 buffers

        // issue staging for t+1 — lands during tile t's compute
        if (t + 1 < NT) {
            const int kn = (t + 1) * BK;
            #pragma unroll
            for (int i = 0; i < 2; ++i) {
                const int J = wave * 2 + i;
                load_lds_16(bSrc + (size_t)(J * 8) * FIN + kn, &Bs[nxt][J * 512]);
            }
            ap0 = *(const float4*)(aSrc + kn + ac * 8);
            ap1 = *(const float4*)(aSrc + kn + ac * 8 + 4);
            ap2 = *(const float4*)(aSrc + kn + (ac + 4) * 8);
            ap3 = *(const float4*)(aSrc + kn + (ac + 4) * 8 + 4);
        }

        // compute tile t: two K=32 halves, frag regs reused across halves
        #pragma unroll
        for (int kk = 0; kk < 2; ++kk) {
            const int c = kk * 4 + quad;   // chunk index 0..7
            short8 af[4], bfr[4];
            #pragma unroll
            for (int mi = 0; mi < 4; ++mi) {
                const int m = wr * 64 + mi * 16 + l16;
                af[mi] = *(const short8*)(&As[cur][m * 64 + ((c ^ (m & 7)) * 8)]);
            }
            #pragma unroll
            for (int ni = 0; ni < 4; ++ni) {
                const int n = wc * 64 + ni * 16 + l16;
                bfr[ni] = *(const short8*)(&Bs[cur][n * 64 + ((c ^ (n & 7)) * 8)]);
            }
            #pragma unroll
            for (int mi = 0; mi < 4; ++mi)
                #pragma unroll
                for (int ni = 0; ni < 4; ++ni)
                    acc[mi][ni] = __builtin_amdgcn_mfma_f32_16x16x32_bf16(
                        af[mi], bfr[ni], acc[mi][ni], 0, 0, 0);
        }
    }

    // ---- fused epilogue. C/D layout: col = lane&15, row = quad*4 + reg.
    // GEMM rows 0-127 (wr 0,1) = stm -> W2[0..511];
    // rows 128-255 (wr 2,3) = nstm -> W2[512..1023]. wr is wave-uniform.
    float b1v[4], w2v[4];
    const float* w2base = (wr < 2) ? W2 : W2 + FOUT;
    #pragma unroll
    for (int ni = 0; ni < 4; ++ni) {
        int col = n0 + wc * 64 + ni * 16 + l16;
        b1v[ni] = b1[col];
        w2v[ni] = w2base[col];
    }

    __syncthreads();                 // all MFMA LDS reads done; reuse As
    float* Epi = (float*)As;         // [256 rows][4 wave-cols] partials (4 KB)

    #pragma unroll
    for (int mi = 0; mi < 4; ++mi) {
        #pragma unroll
        for (int r = 0; r < 4; ++r) {
            float s = 0.0f;
            #pragma unroll
            for (int ni = 0; ni < 4; ++ni) {
                float h = acc[mi][ni][r] + b1v[ni];
                h = fminf(fmaxf(h, 0.0f), 1.0f);
                s += h * w2v[ni];
            }
            s += __shfl_xor(s, 1);
            s += __shfl_xor(s, 2);
            s += __shfl_xor(s, 4);
            s += __shfl_xor(s, 8);
            if (l16 == 0) {
                Epi[(wr * 64 + mi * 16 + quad * 4 + r) * 4 + wc] = s;
            }
        }
    }
    __syncthreads();

    // batch row i partial over this block's 256 features =
    // stm-row i partials (rows 0-127) + nstm-row i partials (128-255)
    if (tid < BM) {
        float x = 0.0f;
        #pragma unroll
        for (int j = 0; j < 4; ++j)
            x += Epi[tid * 4 + j] + Epi[(tid + BM) * 4 + j];
        P[n_idx * BATCH + b0 + tid] = x;
    }
}

// sum the two N-half partials + bias, sigmoid
__global__ __launch_bounds__(256) void finish(
    const float* __restrict__ P, const float* __restrict__ b2,
    float* __restrict__ out)
{
    int i = blockIdx.x * 256 + threadIdx.x;
    float x = b2[0] + P[i] + P[BATCH + i];
    out[i] = 1.0f / (1.0f + expf(-x));
}

extern "C" void kernel_launch(void* const* d_in, const int* in_sizes, int n_in,
                              void* d_out, int out_size, void* d_ws, size_t ws_size,
                              hipStream_t stream)
{
    (void)in_sizes; (void)n_in; (void)out_size; (void)ws_size;
    const float* stm  = (const float*)d_in[0];
    const float* nstm = (const float*)d_in[1];
    const float* W1   = (const float*)d_in[2];
    const float* b1   = (const float*)d_in[3];
    const float* W2   = (const float*)d_in[4];
    const float* b2   = (const float*)d_in[5];
    float* out = (float*)d_out;
    unsigned short* W1b = (unsigned short*)d_ws;           // bf16 W1 (768 KB)
    float* P = (float*)((char*)d_ws + FOUT * FIN * 2);     // partials (128 KB)

    cvt_w1<<<dim3((FOUT * FIN) / (256 * 8)), dim3(256), 0, stream>>>(W1, W1b);
    pn_gemm<<<dim3((BATCH / BM) * 2), dim3(1024), 0, stream>>>(
        stm, nstm, W1b, b1, W2, P);
    finish<<<dim3(BATCH / 256), dim3(256), 0, stream>>>(P, b2, out);
}